// Round 15
// baseline (451.951 us; speedup 1.0000x reference)
//
#include <hip/hip_runtime.h>

// GCN link predictor, fp32 — round 15: paired-node aggregation.
//  r14 budget: 3x aggregate ~195us is the biggest bucket, ~2x its L3-BW floor
//  (latency-bound: 2 serial load-latencies per 8 edges). New aggregate: one wave
//  handles 2 ADJACENT nodes (contiguous CSR ranges), interleaving their 8-deep
//  batches -> 16 loads in flight, 2 latencies per 16 edges.
//  Everything else byte-identical to r14 (450us).
//
// ws layout (float units):
//   0        norm_src [N]
//   100000   norm_dst [N]
//   200000   cursor (int) [N]
//   300000   deg_in (int) [N]
//   400000   row_ptr (int) [N+1]
//   500004   cedge (float4) [E]        (src, ns*w_l0, ns*w_l1, ns*w_l2)
//   4500004  hw   [N*64]  (pre-layer0: deg replicas 16N ints + scan scratch)
//   10900004 agg  [N*64]
// total 17300004 floats = 69.2 MB

#define NN 100000
#define NE 1000000
#define NP 100000
#define SCAN_NB 98
#define NT 1563
#define CSRB 2048

__device__ __forceinline__ void row_fma(float4& acc, float xv, const float4& wv) {
    acc.x = fmaf(xv, wv.x, acc.x);
    acc.y = fmaf(xv, wv.y, acc.y);
    acc.z = fmaf(xv, wv.z, acc.z);
    acc.w = fmaf(xv, wv.w, acc.w);
}

// per-XCD replicated degree count: atomics stay in the local (XCD) L2.
__global__ void deg_kernel(const int4* __restrict__ src4, const int4* __restrict__ dst4,
                           int* __restrict__ repl, int E4) {
    int xcc;
    asm volatile("s_getreg_b32 %0, hwreg(HW_REG_XCC_ID)" : "=s"(xcc));
    xcc &= 7;
    int* dout = repl + xcc * NN;
    int* din  = repl + (8 + xcc) * NN;
    int tid = blockIdx.x * blockDim.x + threadIdx.x;
    if (tid < E4) {
        int4 s = src4[tid], d = dst4[tid];
        __hip_atomic_fetch_add(&dout[s.x], 1, __ATOMIC_RELAXED, __HIP_MEMORY_SCOPE_WORKGROUP);
        __hip_atomic_fetch_add(&dout[s.y], 1, __ATOMIC_RELAXED, __HIP_MEMORY_SCOPE_WORKGROUP);
        __hip_atomic_fetch_add(&dout[s.z], 1, __ATOMIC_RELAXED, __HIP_MEMORY_SCOPE_WORKGROUP);
        __hip_atomic_fetch_add(&dout[s.w], 1, __ATOMIC_RELAXED, __HIP_MEMORY_SCOPE_WORKGROUP);
        __hip_atomic_fetch_add(&din[d.x], 1, __ATOMIC_RELAXED, __HIP_MEMORY_SCOPE_WORKGROUP);
        __hip_atomic_fetch_add(&din[d.y], 1, __ATOMIC_RELAXED, __HIP_MEMORY_SCOPE_WORKGROUP);
        __hip_atomic_fetch_add(&din[d.z], 1, __ATOMIC_RELAXED, __HIP_MEMORY_SCOPE_WORKGROUP);
        __hip_atomic_fetch_add(&din[d.w], 1, __ATOMIC_RELAXED, __HIP_MEMORY_SCOPE_WORKGROUP);
    }
}

__global__ void reduce_norm_kernel(const int* __restrict__ repl, float* __restrict__ norm_src,
                                   float* __restrict__ norm_dst, int* __restrict__ deg_in, int n) {
    int i = blockIdx.x * blockDim.x + threadIdx.x;
    if (i < n) {
        int so = 0, si = 0;
#pragma unroll
        for (int x = 0; x < 8; ++x) {
            so += repl[x * NN + i];
            si += repl[(8 + x) * NN + i];
        }
        norm_src[i] = rsqrtf(fmaxf((float)so, 1.0f));
        norm_dst[i] = rsqrtf(fmaxf((float)si, 1.0f));
        deg_in[i] = si;
    }
}

__global__ __launch_bounds__(1024) void scan_block(const int* __restrict__ deg,
                                                   int* __restrict__ tmp_excl,
                                                   int* __restrict__ blocksums, int n) {
    __shared__ int wsums[16];
    const int i = blockIdx.x * 1024 + threadIdx.x;
    const int lane = threadIdx.x & 63, w = threadIdx.x >> 6;
    int v = (i < n) ? deg[i] : 0;
    int s = v;
#pragma unroll
    for (int off = 1; off < 64; off <<= 1) {
        int u = __shfl_up(s, off, 64);
        if (lane >= off) s += u;
    }
    if (lane == 63) wsums[w] = s;
    __syncthreads();
    if (w == 0) {
        int wv = (lane < 16) ? wsums[lane] : 0;
#pragma unroll
        for (int off = 1; off < 16; off <<= 1) {
            int u = __shfl_up(wv, off, 64);
            if (lane >= off) wv += u;
        }
        if (lane < 16) wsums[lane] = wv;
    }
    __syncthreads();
    int excl = s - v + (w > 0 ? wsums[w - 1] : 0);
    if (i < n) tmp_excl[i] = excl;
    if (threadIdx.x == 1023) blocksums[blockIdx.x] = excl + v;
}

__global__ void scan_sums(int* __restrict__ bs, int nb) {
    __shared__ int wtot[2];
    const int t = threadIdx.x;  // 128 threads
    const int lane = t & 63, w = t >> 6;
    int v = (t < nb) ? bs[t] : 0;
    int s = v;
#pragma unroll
    for (int off = 1; off < 64; off <<= 1) {
        int u = __shfl_up(s, off, 64);
        if (lane >= off) s += u;
    }
    if (lane == 63) wtot[w] = s;
    __syncthreads();
    int excl = s - v + (w == 1 ? wtot[0] : 0);
    if (t < nb) bs[t] = excl;
}

__global__ __launch_bounds__(1024) void scan_apply(const int* __restrict__ tmp_excl,
                                                   const int* __restrict__ bs,
                                                   int* __restrict__ row_ptr,
                                                   int* __restrict__ cursor, int n) {
    const int i = blockIdx.x * 1024 + threadIdx.x;
    if (i < n) {
        int r = tmp_excl[i] + bs[blockIdx.x];
        row_ptr[i] = r;
        cursor[i] = r;
    }
    if (i == 0) row_ptr[n] = NE;
}

// FUSED: blocks [0,NT) run gemm0 (hw = x @ W0); blocks [NT,NT+CSRB) run csr_fill.
__global__ __launch_bounds__(256) void csr_gemm0_fused(
        const int* __restrict__ src, const int* __restrict__ dst,
        const float* __restrict__ ew, const float* __restrict__ norm_src,
        int* __restrict__ cursor, float4* __restrict__ cedge,
        const float* __restrict__ in, const float* __restrict__ W,
        float* __restrict__ out, int n) {
    __shared__ float Ws[128 * 64];
    const int tid = threadIdx.x;

    if (blockIdx.x < NT) {
        for (int i = tid; i < 128 * 16; i += 256) ((float4*)Ws)[i] = ((const float4*)W)[i];
        __syncthreads();

        const int tr = tid >> 4, tc = tid & 15;
        const int row0 = blockIdx.x * 64 + tr * 4;
        const float* xr0 = in + (size_t)min(row0 + 0, n - 1) * 128;
        const float* xr1 = in + (size_t)min(row0 + 1, n - 1) * 128;
        const float* xr2 = in + (size_t)min(row0 + 2, n - 1) * 128;
        const float* xr3 = in + (size_t)min(row0 + 3, n - 1) * 128;

        float4 acc0 = {0, 0, 0, 0}, acc1 = {0, 0, 0, 0}, acc2 = {0, 0, 0, 0}, acc3 = {0, 0, 0, 0};
#pragma unroll 4
        for (int k4 = 0; k4 < 32; ++k4) {
            const int kb = k4 * 4;
            float4 xv0 = *(const float4*)&xr0[kb];
            float4 xv1 = *(const float4*)&xr1[kb];
            float4 xv2 = *(const float4*)&xr2[kb];
            float4 xv3 = *(const float4*)&xr3[kb];
            const float* wb = &Ws[kb * 64 + tc * 4];
            float4 wk;
            wk = *(const float4*)(wb);
            row_fma(acc0, xv0.x, wk); row_fma(acc1, xv1.x, wk); row_fma(acc2, xv2.x, wk); row_fma(acc3, xv3.x, wk);
            wk = *(const float4*)(wb + 64);
            row_fma(acc0, xv0.y, wk); row_fma(acc1, xv1.y, wk); row_fma(acc2, xv2.y, wk); row_fma(acc3, xv3.y, wk);
            wk = *(const float4*)(wb + 128);
            row_fma(acc0, xv0.z, wk); row_fma(acc1, xv1.z, wk); row_fma(acc2, xv2.z, wk); row_fma(acc3, xv3.z, wk);
            wk = *(const float4*)(wb + 192);
            row_fma(acc0, xv0.w, wk); row_fma(acc1, xv1.w, wk); row_fma(acc2, xv2.w, wk); row_fma(acc3, xv3.w, wk);
        }

#pragma unroll
        for (int i = 0; i < 4; ++i) {
            int row = row0 + i;
            if (row < n) {
                float4 o = (i == 0) ? acc0 : (i == 1) ? acc1 : (i == 2) ? acc2 : acc3;
                *(float4*)&out[row * 64 + tc * 4] = o;
            }
        }
    } else {
        int t = (blockIdx.x - NT) * 256 + tid;
        int stride = CSRB * 256;
        for (int e = t; e < NE; e += stride) {
            int s = src[e];
            int d = dst[e];
            float nsv = norm_src[s];
            int slot = atomicAdd(&cursor[d], 1);
            float4 c;
            c.x = __int_as_float(s);
            c.y = ew[e] * nsv;
            c.z = ew[NE + e] * nsv;
            c.w = ew[2 * NE + e] * nsv;
            cedge[slot] = c;
        }
    }
}

// weight selector (function, not macro — r4 lesson)
template <int WSEL>
__device__ __forceinline__ float esel(const float4& c) {
    return (WSEL == 0) ? c.y : (WSEL == 1) ? c.z : c.w;
}

// Paired-node CSR aggregation: one wave per 2 ADJACENT nodes (contiguous CSR
// ranges). Main loop keeps 16 edge-descriptor loads in flight (8 per node),
// hiding node B's cedge latency under node A's gather wait.
template <int WSEL, bool RELU>
__global__ __launch_bounds__(256) void aggregate(const float* __restrict__ hw,
                                                 const float4* __restrict__ cedge,
                                                 const int* __restrict__ row_ptr,
                                                 const float* __restrict__ norm_dst,
                                                 const float* __restrict__ bias,
                                                 float* __restrict__ outx, int n) {
    const int lane = threadIdx.x & 63;
    const int gw = (blockIdx.x * blockDim.x + threadIdx.x) >> 6;
    const int nw = (gridDim.x * blockDim.x) >> 6;
    const float blane = bias[lane];
    const int npairs = n >> 1;  // n = 100000, even
    for (int p = gw; p < npairs; p += nw) {
        const int nodeA = 2 * p;
        int iA = row_ptr[nodeA];
        const int endA = row_ptr[nodeA + 1];  // == start of B (adjacent)
        int iB = endA;
        const int endB = row_ptr[nodeA + 2];
        float aA0 = 0.f, aA1 = 0.f, aA2 = 0.f, aA3 = 0.f;
        float aB0 = 0.f, aB1 = 0.f, aB2 = 0.f, aB3 = 0.f;

        // joint loop: 16 cedge loads in flight, then 16 gathers
        while (iA + 7 < endA && iB + 7 < endB) {
            float4 cA0 = cedge[iA + 0], cA1 = cedge[iA + 1], cA2 = cedge[iA + 2], cA3 = cedge[iA + 3];
            float4 cA4 = cedge[iA + 4], cA5 = cedge[iA + 5], cA6 = cedge[iA + 6], cA7 = cedge[iA + 7];
            float4 cB0 = cedge[iB + 0], cB1 = cedge[iB + 1], cB2 = cedge[iB + 2], cB3 = cedge[iB + 3];
            float4 cB4 = cedge[iB + 4], cB5 = cedge[iB + 5], cB6 = cedge[iB + 6], cB7 = cedge[iB + 7];
            float hA0 = hw[__float_as_int(cA0.x) * 64 + lane];
            float hA1 = hw[__float_as_int(cA1.x) * 64 + lane];
            float hA2 = hw[__float_as_int(cA2.x) * 64 + lane];
            float hA3 = hw[__float_as_int(cA3.x) * 64 + lane];
            float hA4 = hw[__float_as_int(cA4.x) * 64 + lane];
            float hA5 = hw[__float_as_int(cA5.x) * 64 + lane];
            float hA6 = hw[__float_as_int(cA6.x) * 64 + lane];
            float hA7 = hw[__float_as_int(cA7.x) * 64 + lane];
            float hB0 = hw[__float_as_int(cB0.x) * 64 + lane];
            float hB1 = hw[__float_as_int(cB1.x) * 64 + lane];
            float hB2 = hw[__float_as_int(cB2.x) * 64 + lane];
            float hB3 = hw[__float_as_int(cB3.x) * 64 + lane];
            float hB4 = hw[__float_as_int(cB4.x) * 64 + lane];
            float hB5 = hw[__float_as_int(cB5.x) * 64 + lane];
            float hB6 = hw[__float_as_int(cB6.x) * 64 + lane];
            float hB7 = hw[__float_as_int(cB7.x) * 64 + lane];
            aA0 = fmaf(hA0, esel<WSEL>(cA0), aA0);
            aA1 = fmaf(hA1, esel<WSEL>(cA1), aA1);
            aA2 = fmaf(hA2, esel<WSEL>(cA2), aA2);
            aA3 = fmaf(hA3, esel<WSEL>(cA3), aA3);
            aA0 = fmaf(hA4, esel<WSEL>(cA4), aA0);
            aA1 = fmaf(hA5, esel<WSEL>(cA5), aA1);
            aA2 = fmaf(hA6, esel<WSEL>(cA6), aA2);
            aA3 = fmaf(hA7, esel<WSEL>(cA7), aA3);
            aB0 = fmaf(hB0, esel<WSEL>(cB0), aB0);
            aB1 = fmaf(hB1, esel<WSEL>(cB1), aB1);
            aB2 = fmaf(hB2, esel<WSEL>(cB2), aB2);
            aB3 = fmaf(hB3, esel<WSEL>(cB3), aB3);
            aB0 = fmaf(hB4, esel<WSEL>(cB4), aB0);
            aB1 = fmaf(hB5, esel<WSEL>(cB5), aB1);
            aB2 = fmaf(hB6, esel<WSEL>(cB6), aB2);
            aB3 = fmaf(hB7, esel<WSEL>(cB7), aB3);
            iA += 8;
            iB += 8;
        }
        // tail A (8 / 2 / 1)
        for (; iA + 7 < endA; iA += 8) {
            float4 c0 = cedge[iA + 0], c1 = cedge[iA + 1], c2 = cedge[iA + 2], c3 = cedge[iA + 3];
            float4 c4 = cedge[iA + 4], c5 = cedge[iA + 5], c6 = cedge[iA + 6], c7 = cedge[iA + 7];
            float h0 = hw[__float_as_int(c0.x) * 64 + lane];
            float h1 = hw[__float_as_int(c1.x) * 64 + lane];
            float h2 = hw[__float_as_int(c2.x) * 64 + lane];
            float h3 = hw[__float_as_int(c3.x) * 64 + lane];
            float h4 = hw[__float_as_int(c4.x) * 64 + lane];
            float h5 = hw[__float_as_int(c5.x) * 64 + lane];
            float h6 = hw[__float_as_int(c6.x) * 64 + lane];
            float h7 = hw[__float_as_int(c7.x) * 64 + lane];
            aA0 = fmaf(h0, esel<WSEL>(c0), aA0);
            aA1 = fmaf(h1, esel<WSEL>(c1), aA1);
            aA2 = fmaf(h2, esel<WSEL>(c2), aA2);
            aA3 = fmaf(h3, esel<WSEL>(c3), aA3);
            aA0 = fmaf(h4, esel<WSEL>(c4), aA0);
            aA1 = fmaf(h5, esel<WSEL>(c5), aA1);
            aA2 = fmaf(h6, esel<WSEL>(c6), aA2);
            aA3 = fmaf(h7, esel<WSEL>(c7), aA3);
        }
        for (; iA + 1 < endA; iA += 2) {
            float4 c0 = cedge[iA], c1 = cedge[iA + 1];
            float h0 = hw[__float_as_int(c0.x) * 64 + lane];
            float h1 = hw[__float_as_int(c1.x) * 64 + lane];
            aA0 = fmaf(h0, esel<WSEL>(c0), aA0);
            aA1 = fmaf(h1, esel<WSEL>(c1), aA1);
        }
        if (iA < endA) {
            float4 c0 = cedge[iA];
            aA0 = fmaf(hw[__float_as_int(c0.x) * 64 + lane], esel<WSEL>(c0), aA0);
        }
        // tail B (8 / 2 / 1)
        for (; iB + 7 < endB; iB += 8) {
            float4 c0 = cedge[iB + 0], c1 = cedge[iB + 1], c2 = cedge[iB + 2], c3 = cedge[iB + 3];
            float4 c4 = cedge[iB + 4], c5 = cedge[iB + 5], c6 = cedge[iB + 6], c7 = cedge[iB + 7];
            float h0 = hw[__float_as_int(c0.x) * 64 + lane];
            float h1 = hw[__float_as_int(c1.x) * 64 + lane];
            float h2 = hw[__float_as_int(c2.x) * 64 + lane];
            float h3 = hw[__float_as_int(c3.x) * 64 + lane];
            float h4 = hw[__float_as_int(c4.x) * 64 + lane];
            float h5 = hw[__float_as_int(c5.x) * 64 + lane];
            float h6 = hw[__float_as_int(c6.x) * 64 + lane];
            float h7 = hw[__float_as_int(c7.x) * 64 + lane];
            aB0 = fmaf(h0, esel<WSEL>(c0), aB0);
            aB1 = fmaf(h1, esel<WSEL>(c1), aB1);
            aB2 = fmaf(h2, esel<WSEL>(c2), aB2);
            aB3 = fmaf(h3, esel<WSEL>(c3), aB3);
            aB0 = fmaf(h4, esel<WSEL>(c4), aB0);
            aB1 = fmaf(h5, esel<WSEL>(c5), aB1);
            aB2 = fmaf(h6, esel<WSEL>(c6), aB2);
            aB3 = fmaf(h7, esel<WSEL>(c7), aB3);
        }
        for (; iB + 1 < endB; iB += 2) {
            float4 c0 = cedge[iB], c1 = cedge[iB + 1];
            float h0 = hw[__float_as_int(c0.x) * 64 + lane];
            float h1 = hw[__float_as_int(c1.x) * 64 + lane];
            aB0 = fmaf(h0, esel<WSEL>(c0), aB0);
            aB1 = fmaf(h1, esel<WSEL>(c1), aB1);
        }
        if (iB < endB) {
            float4 c0 = cedge[iB];
            aB0 = fmaf(hw[__float_as_int(c0.x) * 64 + lane], esel<WSEL>(c0), aB0);
        }

        float aA = (aA0 + aA1) + (aA2 + aA3);
        float aB = (aB0 + aB1) + (aB2 + aB3);
        float tA = fmaf(aA, norm_dst[nodeA], blane);
        float tB = fmaf(aB, norm_dst[nodeA + 1], blane);
        if (RELU) {
            tA = fmaxf(tA, 0.f);
            tB = fmaxf(tB, 0.f);
        }
        outx[nodeA * 64 + lane] = tA;
        outx[(nodeA + 1) * 64 + lane] = tB;
    }
}

// Streaming 64-row GEMM tile (r7-exact body): W in LDS once, X direct from global.
template <int K>
__global__ __launch_bounds__(256, 5) void gemm_tile(const float* __restrict__ in,
                                                    const float* __restrict__ W,
                                                    float* __restrict__ out, int n) {
    __shared__ float Ws[K * 64];
    const int tid = threadIdx.x;
    for (int i = tid; i < K * 16; i += 256) ((float4*)Ws)[i] = ((const float4*)W)[i];
    __syncthreads();  // the only barrier in the kernel

    const int tr = tid >> 4, tc = tid & 15;
    const int row0 = blockIdx.x * 64 + tr * 4;
    const float* xr0 = in + (size_t)min(row0 + 0, n - 1) * K;
    const float* xr1 = in + (size_t)min(row0 + 1, n - 1) * K;
    const float* xr2 = in + (size_t)min(row0 + 2, n - 1) * K;
    const float* xr3 = in + (size_t)min(row0 + 3, n - 1) * K;

    float4 acc0 = {0, 0, 0, 0}, acc1 = {0, 0, 0, 0}, acc2 = {0, 0, 0, 0}, acc3 = {0, 0, 0, 0};
#pragma unroll 4
    for (int k4 = 0; k4 < K / 4; ++k4) {
        const int kb = k4 * 4;
        float4 xv0 = *(const float4*)&xr0[kb];
        float4 xv1 = *(const float4*)&xr1[kb];
        float4 xv2 = *(const float4*)&xr2[kb];
        float4 xv3 = *(const float4*)&xr3[kb];
        const float* wb = &Ws[kb * 64 + tc * 4];
        float4 wk;
        wk = *(const float4*)(wb);
        row_fma(acc0, xv0.x, wk); row_fma(acc1, xv1.x, wk); row_fma(acc2, xv2.x, wk); row_fma(acc3, xv3.x, wk);
        wk = *(const float4*)(wb + 64);
        row_fma(acc0, xv0.y, wk); row_fma(acc1, xv1.y, wk); row_fma(acc2, xv2.y, wk); row_fma(acc3, xv3.y, wk);
        wk = *(const float4*)(wb + 128);
        row_fma(acc0, xv0.z, wk); row_fma(acc1, xv1.z, wk); row_fma(acc2, xv2.z, wk); row_fma(acc3, xv3.z, wk);
        wk = *(const float4*)(wb + 192);
        row_fma(acc0, xv0.w, wk); row_fma(acc1, xv1.w, wk); row_fma(acc2, xv2.w, wk); row_fma(acc3, xv3.w, wk);
    }

#pragma unroll
    for (int i = 0; i < 4; ++i) {
        int row = row0 + i;
        if (row < n) {
            float4 o = (i == 0) ? acc0 : (i == 1) ? acc1 : (i == 2) ? acc2 : acc3;
            *(float4*)&out[row * 64 + tc * 4] = o;
        }
    }
}

#define ZST 76  // Zs row stride

// 64 pairs per block (grid = 3125), float4-coalesced gather (r13-exact).
__global__ __launch_bounds__(256) void mlp_tile(const float* __restrict__ hfin,
                                                const float* __restrict__ P0,
                                                const float* __restrict__ pb0,
                                                const float* __restrict__ P1,
                                                const float* __restrict__ pb1,
                                                const float* __restrict__ P2,
                                                const float* __restrict__ pb2,
                                                const int* __restrict__ pos_src,
                                                const int* __restrict__ pos_dst,
                                                const int* __restrict__ neg_src,
                                                const int* __restrict__ neg_dst,
                                                float* __restrict__ out, int P) {
    __shared__ float Zs[64][ZST];
    __shared__ float pb0s[64], pb1s[64], P2s[64];
    __shared__ int pas[64], pbs[64];
    const int tid = threadIdx.x;
    const int base = blockIdx.x << 6;
    if (tid < 64) {
        pb0s[tid] = pb0[tid];
        pb1s[tid] = pb1[tid];
        P2s[tid] = P2[tid];
        int p = base + tid;
        pas[tid] = (p < P) ? pos_src[p] : neg_src[p - P];
        pbs[tid] = (p < P) ? pos_dst[p] : neg_dst[p - P];
    }
    const float pb2v = pb2[0];
    const int lane = tid & 63, w = tid >> 6;
    const int tr = tid >> 4, tc = tid & 15;
    __syncthreads();

    // gather + product, float4-coalesced: wave w owns pairs [w*16, w*16+16).
    {
        const int sub = lane >> 4;
        const int c4 = (lane & 15) * 4;
        float4 ha[4], hb[4];
#pragma unroll
        for (int r = 0; r < 4; ++r) {
            const int pi = w * 16 + r * 4 + sub;
            ha[r] = *(const float4*)&hfin[pas[pi] * 64 + c4];
            hb[r] = *(const float4*)&hfin[pbs[pi] * 64 + c4];
        }
#pragma unroll
        for (int r = 0; r < 4; ++r) {
            const int pi = w * 16 + r * 4 + sub;
            float4 z;
            z.x = ha[r].x * hb[r].x;
            z.y = ha[r].y * hb[r].y;
            z.z = ha[r].z * hb[r].z;
            z.w = ha[r].w * hb[r].w;
            *(float4*)&Zs[pi][c4] = z;
        }
    }
    __syncthreads();

    // layer 0: Z1 = relu(Z @ P0 + pb0)
    float4 acc0, acc1, acc2, acc3;
    {
        float4 binit = *(const float4*)&pb0s[tc * 4];
        acc0 = binit; acc1 = binit; acc2 = binit; acc3 = binit;
    }
#pragma unroll 4
    for (int k4 = 0; k4 < 16; ++k4) {
        const int kb = k4 * 4;
        float4 xv0 = *(const float4*)&Zs[tr * 4 + 0][kb];
        float4 xv1 = *(const float4*)&Zs[tr * 4 + 1][kb];
        float4 xv2 = *(const float4*)&Zs[tr * 4 + 2][kb];
        float4 xv3 = *(const float4*)&Zs[tr * 4 + 3][kb];
        const float* wb = &P0[kb * 64 + tc * 4];
        float4 wk;
        wk = *(const float4*)(wb);
        row_fma(acc0, xv0.x, wk); row_fma(acc1, xv1.x, wk); row_fma(acc2, xv2.x, wk); row_fma(acc3, xv3.x, wk);
        wk = *(const float4*)(wb + 64);
        row_fma(acc0, xv0.y, wk); row_fma(acc1, xv1.y, wk); row_fma(acc2, xv2.y, wk); row_fma(acc3, xv3.y, wk);
        wk = *(const float4*)(wb + 128);
        row_fma(acc0, xv0.z, wk); row_fma(acc1, xv1.z, wk); row_fma(acc2, xv2.z, wk); row_fma(acc3, xv3.z, wk);
        wk = *(const float4*)(wb + 192);
        row_fma(acc0, xv0.w, wk); row_fma(acc1, xv1.w, wk); row_fma(acc2, xv2.w, wk); row_fma(acc3, xv3.w, wk);
    }
    __syncthreads();
#pragma unroll
    for (int i = 0; i < 4; ++i) {
        float4 o = (i == 0) ? acc0 : (i == 1) ? acc1 : (i == 2) ? acc2 : acc3;
        o.x = fmaxf(o.x, 0.f); o.y = fmaxf(o.y, 0.f); o.z = fmaxf(o.z, 0.f); o.w = fmaxf(o.w, 0.f);
        *(float4*)&Zs[tr * 4 + i][tc * 4] = o;
    }
    __syncthreads();

    // layer 1: Z2 = relu(Z1 @ P1 + pb1)
    {
        float4 binit = *(const float4*)&pb1s[tc * 4];
        acc0 = binit; acc1 = binit; acc2 = binit; acc3 = binit;
    }
#pragma unroll 4
    for (int k4 = 0; k4 < 16; ++k4) {
        const int kb = k4 * 4;
        float4 xv0 = *(const float4*)&Zs[tr * 4 + 0][kb];
        float4 xv1 = *(const float4*)&Zs[tr * 4 + 1][kb];
        float4 xv2 = *(const float4*)&Zs[tr * 4 + 2][kb];
        float4 xv3 = *(const float4*)&Zs[tr * 4 + 3][kb];
        const float* wb = &P1[kb * 64 + tc * 4];
        float4 wk;
        wk = *(const float4*)(wb);
        row_fma(acc0, xv0.x, wk); row_fma(acc1, xv1.x, wk); row_fma(acc2, xv2.x, wk); row_fma(acc3, xv3.x, wk);
        wk = *(const float4*)(wb + 64);
        row_fma(acc0, xv0.y, wk); row_fma(acc1, xv1.y, wk); row_fma(acc2, xv2.y, wk); row_fma(acc3, xv3.y, wk);
        wk = *(const float4*)(wb + 128);
        row_fma(acc0, xv0.z, wk); row_fma(acc1, xv1.z, wk); row_fma(acc2, xv2.z, wk); row_fma(acc3, xv3.z, wk);
        wk = *(const float4*)(wb + 192);
        row_fma(acc0, xv0.w, wk); row_fma(acc1, xv1.w, wk); row_fma(acc2, xv2.w, wk); row_fma(acc3, xv3.w, wk);
    }
    __syncthreads();
#pragma unroll
    for (int i = 0; i < 4; ++i) {
        float4 o = (i == 0) ? acc0 : (i == 1) ? acc1 : (i == 2) ? acc2 : acc3;
        o.x = fmaxf(o.x, 0.f); o.y = fmaxf(o.y, 0.f); o.z = fmaxf(o.z, 0.f); o.w = fmaxf(o.w, 0.f);
        *(float4*)&Zs[tr * 4 + i][tc * 4] = o;
    }
    __syncthreads();

    // final GEMV: out[p] = Z2[p] . P2 + pb2
    {
        int p = tid >> 2, kq = tid & 3;
        float s = 0.f;
#pragma unroll
        for (int i = 0; i < 16; ++i) s = fmaf(Zs[p][kq * 16 + i], P2s[kq * 16 + i], s);
        s += __shfl_xor(s, 1, 64);
        s += __shfl_xor(s, 2, 64);
        if (kq == 0) out[base + p] = s + pb2v;
    }
}

extern "C" void kernel_launch(void* const* d_in, const int* in_sizes, int n_in,
                              void* d_out, int out_size, void* d_ws, size_t ws_size,
                              hipStream_t stream) {
    const float* x     = (const float*)d_in[0];
    const float* ew    = (const float*)d_in[1];  // (3, E)
    const int* src     = (const int*)d_in[2];
    const int* dst     = (const int*)d_in[3];
    const int* pos_src = (const int*)d_in[4];
    const int* pos_dst = (const int*)d_in[5];
    const int* neg_src = (const int*)d_in[6];
    const int* neg_dst = (const int*)d_in[7];
    const float* W0    = (const float*)d_in[8];
    const float* b0    = (const float*)d_in[9];
    const float* W1    = (const float*)d_in[10];
    const float* b1    = (const float*)d_in[11];
    const float* W2    = (const float*)d_in[12];
    const float* b2    = (const float*)d_in[13];
    const float* P0    = (const float*)d_in[14];
    const float* pb0   = (const float*)d_in[15];
    const float* P1    = (const float*)d_in[16];
    const float* pb1   = (const float*)d_in[17];
    const float* P2    = (const float*)d_in[18];
    const float* pb2   = (const float*)d_in[19];
    float* out = (float*)d_out;

    float* ws = (float*)d_ws;
    float* norm_src = ws;                     // N
    float* norm_dst = ws + 100000;            // N
    int* cursor     = (int*)(ws + 200000);    // N
    int* deg_in     = (int*)(ws + 300000);    // N
    int* row_ptr    = (int*)(ws + 400000);    // N+1
    float4* cedge   = (float4*)(ws + 500004); // E
    float* hw       = ws + 4500004;           // N*64
    float* agg      = ws + 10900004;          // N*64

    int* repl      = (int*)hw;            // 16*NN ints (dead before fused launch)
    int* tmp_excl  = (int*)hw + 16 * NN;  // NN
    int* blocksums = (int*)hw + 17 * NN;  // SCAN_NB

    hipMemsetAsync(repl, 0, 16 * NN * sizeof(int), stream);
    deg_kernel<<<(NE / 4 + 255) / 256, 256, 0, stream>>>((const int4*)src, (const int4*)dst,
                                                         repl, NE / 4);
    reduce_norm_kernel<<<(NN + 255) / 256, 256, 0, stream>>>(repl, norm_src, norm_dst, deg_in, NN);
    scan_block<<<SCAN_NB, 1024, 0, stream>>>(deg_in, tmp_excl, blocksums, NN);
    scan_sums<<<1, 128, 0, stream>>>(blocksums, SCAN_NB);
    scan_apply<<<SCAN_NB, 1024, 0, stream>>>(tmp_excl, blocksums, row_ptr, cursor, NN);

    // FUSED: csr_fill (2048 blocks) overlapped with gemm0 (1563 blocks)
    csr_gemm0_fused<<<NT + CSRB, 256, 0, stream>>>(src, dst, ew, norm_src, cursor, cedge,
                                                   x, W0, hw, NN);

    aggregate<0, true><<<4096, 256, 0, stream>>>(hw, cedge, row_ptr, norm_dst, b0, agg, NN);
    // layer 1
    gemm_tile<64><<<NT, 256, 0, stream>>>(agg, W1, hw, NN);
    aggregate<1, true><<<4096, 256, 0, stream>>>(hw, cedge, row_ptr, norm_dst, b1, agg, NN);
    // layer 2 (final, no relu)
    gemm_tile<64><<<NT, 256, 0, stream>>>(agg, W2, hw, NN);
    aggregate<2, false><<<4096, 256, 0, stream>>>(hw, cedge, row_ptr, norm_dst, b2, agg, NN);

    // MLP over pos & neg pairs (64 pairs per block)
    mlp_tile<<<(2 * NP) / 64, 256, 0, stream>>>(agg, P0, pb0, P1, pb1, P2, pb2,
                                                pos_src, pos_dst, neg_src, neg_dst, out, NP);
}